// Round 1
// baseline (354.418 us; speedup 1.0000x reference)
//
#include <hip/hip_runtime.h>

typedef unsigned short u16;
typedef float f32x4 __attribute__((ext_vector_type(4)));
typedef int   i32x4 __attribute__((ext_vector_type(4)));
typedef u16   u16x8 __attribute__((ext_vector_type(8)));

__device__ __forceinline__ u16 f2bf(float f) {
  unsigned u = __float_as_uint(f);
  u += 0x7FFFu + ((u >> 16) & 1u);
  return (u16)(u >> 16);
}

__device__ __forceinline__ float tanh_fast(float x) {
  // 1 - 2/(e^{2x}+1); robust: e->inf => 1, e->0 => -1. No NaN for finite x.
  float e = __expf(2.0f * x);
  return 1.0f - 2.0f / (e + 1.0f);
}

__device__ __forceinline__ void mfma_bf16(f32x4& acc, i32x4 a, i32x4 b) {
  asm("v_mfma_f32_16x16x32_bf16 %0, %1, %2, %0" : "+v"(acc) : "v"(a), "v"(b));
}

// ---------------- fp32 -> bf16 cast (RNE), 8 elems/thread ----------------
__global__ __launch_bounds__(256) void cast_kernel(const float* __restrict__ src,
                                                   u16* __restrict__ dst, int n8) {
  int i = blockIdx.x * 256 + threadIdx.x;
  if (i >= n8) return;
  const float4* s = (const float4*)src;
  float4 a = s[2 * i], b = s[2 * i + 1];
  u16x8 o;
  o[0] = f2bf(a.x); o[1] = f2bf(a.y); o[2] = f2bf(a.z); o[3] = f2bf(a.w);
  o[4] = f2bf(b.x); o[5] = f2bf(b.y); o[6] = f2bf(b.z); o[7] = f2bf(b.w);
  *(u16x8*)(dst + (size_t)8 * i) = o;
}

// ---------------- fused GEMM + tanh + weighted reduce over e --------------
// sv[m] = sum_n tanh( sum_k X[m,k] * W[n,k] ) * wv[n]
// Tile: BM=128 rows, this block covers N-range [split*256, split*256+256) as
// 2 n-tiles of 128. K=1024, BK=32. 4 waves in 2x2 grid, 64x64 per wave.
// Grid: blocks 0..255 audio stage (M=8192), 256..767 text stage (M=16384).
__global__ __launch_bounds__(256) void score_kernel(
    const u16* __restrict__ Xa, const u16* __restrict__ Wa,
    const float* __restrict__ wva, float* __restrict__ sva,
    const u16* __restrict__ Xt, const u16* __restrict__ Wt,
    const float* __restrict__ wvt, float* __restrict__ svt) {
  __shared__ u16 At[128 * 32];
  __shared__ u16 Bt[128 * 32];

  int bx = blockIdx.x;
  const u16 *X, *W; const float* wv; float* svout; int mt, split, M;
  if (bx < 256) { X = Xa; W = Wa; wv = wva; svout = sva; M = 8192;  mt = bx >> 2; split = bx & 3; }
  else { bx -= 256; X = Xt; W = Wt; wv = wvt; svout = svt; M = 16384; mt = bx >> 2; split = bx & 3; }

  const int t = threadIdx.x;
  const int wid = t >> 6, lane = t & 63;
  const int wm = wid >> 1, wn = wid & 1;
  const int lane15 = lane & 15, lg = lane >> 4;
  const size_t m_base = (size_t)mt * 128;

  float rs[4][4];
  #pragma unroll
  for (int mi = 0; mi < 4; ++mi)
    #pragma unroll
    for (int r = 0; r < 4; ++r) rs[mi][r] = 0.f;

  // staging: 512 chunks of 8 bf16; thread t does chunks t and 256+t.
  const int li0 = t, li1 = 256 + t;
  const int ar0 = li0 >> 2, ac0 = (li0 & 3) * 8;
  const int ar1 = li1 >> 2, ac1 = (li1 & 3) * 8;

  for (int nt = 0; nt < 2; ++nt) {
    const int n0 = split * 256 + nt * 128;

    f32x4 acc[4][4];
    #pragma unroll
    for (int mi = 0; mi < 4; ++mi)
      #pragma unroll
      for (int ni = 0; ni < 4; ++ni)
        acc[mi][ni] = (f32x4){0.f, 0.f, 0.f, 0.f};

    const u16* Xb = X + m_base * 1024;
    const u16* Wb = W + (size_t)n0 * 1024;

    i32x4 ra0 = *(const i32x4*)(Xb + (size_t)ar0 * 1024 + ac0);
    i32x4 ra1 = *(const i32x4*)(Xb + (size_t)ar1 * 1024 + ac1);
    i32x4 rb0 = *(const i32x4*)(Wb + (size_t)ar0 * 1024 + ac0);
    i32x4 rb1 = *(const i32x4*)(Wb + (size_t)ar1 * 1024 + ac1);

    for (int kt = 0; kt < 32; ++kt) {
      __syncthreads();                 // previous iteration's ds_reads done
      *(i32x4*)(At + li0 * 8) = ra0;
      *(i32x4*)(At + li1 * 8) = ra1;
      *(i32x4*)(Bt + li0 * 8) = rb0;
      *(i32x4*)(Bt + li1 * 8) = rb1;
      __syncthreads();                 // tiles ready
      if (kt < 31) {                   // prefetch next k-tile into regs
        const int k1 = (kt + 1) * 32;
        ra0 = *(const i32x4*)(Xb + (size_t)ar0 * 1024 + k1 + ac0);
        ra1 = *(const i32x4*)(Xb + (size_t)ar1 * 1024 + k1 + ac1);
        rb0 = *(const i32x4*)(Wb + (size_t)ar0 * 1024 + k1 + ac0);
        rb1 = *(const i32x4*)(Wb + (size_t)ar1 * 1024 + k1 + ac1);
      }
      i32x4 af[4], bfr[4];
      #pragma unroll
      for (int mi = 0; mi < 4; ++mi)
        af[mi] = *(const i32x4*)(At + (wm * 64 + mi * 16 + lane15) * 32 + lg * 8);
      #pragma unroll
      for (int ni = 0; ni < 4; ++ni)
        bfr[ni] = *(const i32x4*)(Bt + (wn * 64 + ni * 16 + lane15) * 32 + lg * 8);
      #pragma unroll
      for (int mi = 0; mi < 4; ++mi)
        #pragma unroll
        for (int ni = 0; ni < 4; ++ni)
          mfma_bf16(acc[mi][ni], af[mi], bfr[ni]);
    }

    // epilogue: fold tanh(C[m,n]) * wv[n] into per-row partials.
    // C/D layout (m89-verified): col = lane&15, row = (lane>>4)*4 + reg
    float wvn[4];
    #pragma unroll
    for (int ni = 0; ni < 4; ++ni) wvn[ni] = wv[n0 + wn * 64 + ni * 16 + lane15];
    #pragma unroll
    for (int mi = 0; mi < 4; ++mi)
      #pragma unroll
      for (int ni = 0; ni < 4; ++ni)
        #pragma unroll
        for (int r = 0; r < 4; ++r)
          rs[mi][r] += tanh_fast(acc[mi][ni][r]) * wvn[ni];
  }

  // reduce over the 16 column-lanes, combine the two wn halves via LDS
  __syncthreads();
  float* sred = (float*)At;
  #pragma unroll
  for (int mi = 0; mi < 4; ++mi)
    #pragma unroll
    for (int r = 0; r < 4; ++r) {
      float v = rs[mi][r];
      v += __shfl_xor(v, 1);
      v += __shfl_xor(v, 2);
      v += __shfl_xor(v, 4);
      v += __shfl_xor(v, 8);
      if (lane15 == 0) sred[wn * 128 + wm * 64 + mi * 16 + lg * 4 + r] = v;
    }
  __syncthreads();
  if (t < 128) svout[(size_t)split * M + m_base + t] = sred[t] + sred[128 + t];
}

// ---------------- softmax over a + q[b,d] = sum_a p[a]*x[b,a,d] -----------
// grid: 0..255 audio (b=bx>>4, dch=bx&15), 256..511 text. 256 threads.
__global__ __launch_bounds__(256) void softq_kernel(
    const float* __restrict__ xA, const float* __restrict__ svA, float* __restrict__ qA,
    const float* __restrict__ xT, const float* __restrict__ svT, float* __restrict__ qT) {
  int bx = blockIdx.x;
  int stage = bx >> 8;
  int b = (bx >> 4) & 15, dch = bx & 15;
  int Acnt = stage ? 1024 : 512;
  int M = stage ? 16384 : 8192;
  const float* x = stage ? xT : xA;
  const float* svp = stage ? svT : svA;
  float* q = stage ? qT : qA;
  int rowbase = b * Acnt;

  __shared__ float p[1024];
  __shared__ float red[256];
  int t = threadIdx.x;

  float mloc = -1e30f;
  for (int a = t; a < Acnt; a += 256) {
    float v = svp[rowbase + a] + svp[M + rowbase + a] +
              svp[2 * M + rowbase + a] + svp[3 * M + rowbase + a];
    p[a] = v;
    mloc = fmaxf(mloc, v);
  }
  #pragma unroll
  for (int off = 32; off; off >>= 1) mloc = fmaxf(mloc, __shfl_xor(mloc, off));
  if ((t & 63) == 0) red[t >> 6] = mloc;
  __syncthreads();
  float mx = fmaxf(fmaxf(red[0], red[1]), fmaxf(red[2], red[3]));

  float sloc = 0.f;
  for (int a = t; a < Acnt; a += 256) {
    float e = __expf(p[a] - mx);
    p[a] = e;
    sloc += e;
  }
  #pragma unroll
  for (int off = 32; off; off >>= 1) sloc += __shfl_xor(sloc, off);
  __syncthreads();
  if ((t & 63) == 0) red[t >> 6] = sloc;
  __syncthreads();
  float inv = 1.0f / (red[0] + red[1] + red[2] + red[3]);

  int dl = t & 63, ag = t >> 6;
  const float* xb = x + (size_t)rowbase * 1024 + dch * 64 + dl;
  float acc = 0.f;
  #pragma unroll 4
  for (int a = ag; a < Acnt; a += 4) acc += p[a] * xb[(size_t)a * 1024];
  __syncthreads();
  red[t] = acc;
  __syncthreads();
  if (t < 64) {
    float tot = red[t] + red[t + 64] + red[t + 128] + red[t + 192];
    q[b * 1024 + dch * 64 + t] = tot * inv;
  }
}

// ---------------- broadcast q over L into the outputs ---------------------
__global__ __launch_bounds__(256) void bcast_kernel(const float* __restrict__ q2,
                                                    const float* __restrict__ q1,
                                                    float4* __restrict__ out) {
  const size_t HALF = (size_t)16 * 1024 * 256;  // float4s per output half (2^22)
  size_t stride = (size_t)gridDim.x * blockDim.x;
  for (size_t i = (size_t)blockIdx.x * blockDim.x + threadIdx.x; i < 2 * HALF; i += stride) {
    size_t ih = i & (HALF - 1);
    const float4* q = (i < HALF) ? (const float4*)q2 : (const float4*)q1;
    int b = (int)(ih >> 18);   // 1024*256 = 2^18 float4 per batch
    int d4 = (int)(ih & 255);
    out[i] = q[(b << 8) + d4];
  }
}

extern "C" void kernel_launch(void* const* d_in, const int* in_sizes, int n_in,
                              void* d_out, int out_size, void* d_ws, size_t ws_size,
                              hipStream_t stream) {
  const float* text  = (const float*)d_in[0];   // (16,1024,1024)
  const float* audio = (const float*)d_in[1];   // (16, 512,1024)
  const float* Wa1   = (const float*)d_in[4];   // (1024,1024)
  const float* watt1 = (const float*)d_in[5];   // (2048,)
  const float* Wt2   = (const float*)d_in[7];   // (1024,1024)
  const float* watt2 = (const float*)d_in[10];  // (2048,)

  char* ws = (char*)d_ws;
  u16*   tb  = (u16*)(ws);                      // text bf16   33,554,432 B
  u16*   ab  = (u16*)(ws + 33554432);           // audio bf16  16,777,216 B
  u16*   w2b = (u16*)(ws + 50331648);           // Wt2 bf16     2,097,152 B
  u16*   w1b = (u16*)(ws + 52428800);           // Wa1 bf16     2,097,152 B
  float* sv2 = (float*)(ws + 54525952);         // [4][16384]     262,144 B
  float* sv1 = (float*)(ws + 54788096);         // [4][ 8192]     131,072 B
  float* q2  = (float*)(ws + 54919168);         // [16][1024]      65,536 B
  float* q1  = (float*)(ws + 54984704);         // [16][1024]      65,536 B

  cast_kernel<<<8192, 256, 0, stream>>>(text,  tb,  2097152);
  cast_kernel<<<4096, 256, 0, stream>>>(audio, ab,  1048576);
  cast_kernel<<<512,  256, 0, stream>>>(Wt2,   w2b, 131072);
  cast_kernel<<<512,  256, 0, stream>>>(Wa1,   w1b, 131072);

  score_kernel<<<768, 256, 0, stream>>>(ab, w1b, watt1 + 1024, sv1,
                                        tb, w2b, watt2 + 1024, sv2);

  softq_kernel<<<512, 256, 0, stream>>>(audio, sv1, q1, text, sv2, q2);

  bcast_kernel<<<4096, 256, 0, stream>>>(q2, q1, (float4*)d_out);
}

// Round 2
// 349.259 us; speedup vs baseline: 1.0148x; 1.0148x over previous
//
#include <hip/hip_runtime.h>

typedef unsigned short u16;
typedef float f32x4 __attribute__((ext_vector_type(4)));
typedef int   i32x4 __attribute__((ext_vector_type(4)));
typedef u16   u16x8 __attribute__((ext_vector_type(8)));

#define LDS_STRIDE 40  // u16 per row: 80B => bank = (20*row)%32, period 8 -> free 2-way

__device__ __forceinline__ u16 f2bf(float f) {
  unsigned u = __float_as_uint(f);
  u += 0x7FFFu + ((u >> 16) & 1u);
  return (u16)(u >> 16);
}

__device__ __forceinline__ float tanh_fast(float x) {
  float e = __expf(2.0f * x);
  return 1.0f - 2.0f / (e + 1.0f);
}

__device__ __forceinline__ void mfma_bf16(f32x4& acc, i32x4 a, i32x4 b) {
  asm("v_mfma_f32_16x16x32_bf16 %0, %1, %2, %0" : "+v"(acc) : "v"(a), "v"(b));
}

// ------------- fused fp32 -> bf16 cast for all 4 tensors (one launch) -------
// chunk = 8 elements. text 2097152 chunks | audio 1048576 | Wt2 131072 | Wa1 131072
__global__ __launch_bounds__(256) void cast_all_kernel(
    const float* __restrict__ text, const float* __restrict__ audio,
    const float* __restrict__ w2, const float* __restrict__ w1,
    u16* __restrict__ tb, u16* __restrict__ ab,
    u16* __restrict__ w2b, u16* __restrict__ w1b) {
  const int NTOT = 3407872;
  int stride = gridDim.x * 256;
  for (int i = blockIdx.x * 256 + threadIdx.x; i < NTOT; i += stride) {
    const float* src; u16* dst; int j;
    if (i < 2097152)      { src = text;  dst = tb;  j = i; }
    else if (i < 3145728) { src = audio; dst = ab;  j = i - 2097152; }
    else if (i < 3276800) { src = w2;    dst = w2b; j = i - 3145728; }
    else                  { src = w1;    dst = w1b; j = i - 3276800; }
    const float4* s = (const float4*)src;
    float4 a = s[2 * j], b = s[2 * j + 1];
    u16x8 o;
    o[0] = f2bf(a.x); o[1] = f2bf(a.y); o[2] = f2bf(a.z); o[3] = f2bf(a.w);
    o[4] = f2bf(b.x); o[5] = f2bf(b.y); o[6] = f2bf(b.z); o[7] = f2bf(b.w);
    *(u16x8*)(dst + (size_t)8 * j) = o;
  }
}

// ---------------- fused GEMM + tanh + weighted reduce over e --------------
// sv[m] = sum_n tanh( sum_k X[m,k] * W[n,k] ) * wv[n]
// BM=128 rows/block; block covers N-range [split*256, +256) as 2 n-tiles of 128.
// K=1024, BK=32. 4 waves in 2x2. Blocks 0..255 audio (M=8192), 256..767 text.
__global__ __launch_bounds__(256) void score_kernel(
    const u16* __restrict__ Xa, const u16* __restrict__ Wa,
    const float* __restrict__ wva, float* __restrict__ sva,
    const u16* __restrict__ Xt, const u16* __restrict__ Wt,
    const float* __restrict__ wvt, float* __restrict__ svt) {
  __shared__ u16 At[128 * LDS_STRIDE];
  __shared__ u16 Bt[128 * LDS_STRIDE];

  int bx = blockIdx.x;
  const u16 *X, *W; const float* wv; float* svout; int mt, split, M;
  if (bx < 256) { X = Xa; W = Wa; wv = wva; svout = sva; M = 8192;  mt = bx >> 2; split = bx & 3; }
  else { bx -= 256; X = Xt; W = Wt; wv = wvt; svout = svt; M = 16384; mt = bx >> 2; split = bx & 3; }

  const int t = threadIdx.x;
  const int wid = t >> 6, lane = t & 63;
  const int wm = wid >> 1, wn = wid & 1;
  const int lane15 = lane & 15, lg = lane >> 4;
  const size_t m_base = (size_t)mt * 128;

  float rs[4][4];
  #pragma unroll
  for (int mi = 0; mi < 4; ++mi)
    #pragma unroll
    for (int r = 0; r < 4; ++r) rs[mi][r] = 0.f;

  // staging: 512 chunks of 8 bf16; thread t does chunks t and 256+t.
  const int li0 = t, li1 = 256 + t;
  const int ar0 = li0 >> 2, ac0 = (li0 & 3) * 8;
  const int ar1 = li1 >> 2, ac1 = (li1 & 3) * 8;

  for (int nt = 0; nt < 2; ++nt) {
    const int n0 = split * 256 + nt * 128;

    f32x4 acc[4][4];
    #pragma unroll
    for (int mi = 0; mi < 4; ++mi)
      #pragma unroll
      for (int ni = 0; ni < 4; ++ni)
        acc[mi][ni] = (f32x4){0.f, 0.f, 0.f, 0.f};

    const u16* Xb = X + m_base * 1024;
    const u16* Wb = W + (size_t)n0 * 1024;

    i32x4 ra0 = *(const i32x4*)(Xb + (size_t)ar0 * 1024 + ac0);
    i32x4 ra1 = *(const i32x4*)(Xb + (size_t)ar1 * 1024 + ac1);
    i32x4 rb0 = *(const i32x4*)(Wb + (size_t)ar0 * 1024 + ac0);
    i32x4 rb1 = *(const i32x4*)(Wb + (size_t)ar1 * 1024 + ac1);

    for (int kt = 0; kt < 32; ++kt) {
      __syncthreads();                 // previous iteration's ds_reads done
      *(i32x4*)(At + li0 * 8 / 8 * 0 + ar0 * LDS_STRIDE + ac0) = ra0;
      *(i32x4*)(At + ar1 * LDS_STRIDE + ac1) = ra1;
      *(i32x4*)(Bt + ar0 * LDS_STRIDE + ac0) = rb0;
      *(i32x4*)(Bt + ar1 * LDS_STRIDE + ac1) = rb1;
      __syncthreads();                 // tiles ready
      if (kt < 31) {                   // prefetch next k-tile into regs
        const int k1 = (kt + 1) * 32;
        ra0 = *(const i32x4*)(Xb + (size_t)ar0 * 1024 + k1 + ac0);
        ra1 = *(const i32x4*)(Xb + (size_t)ar1 * 1024 + k1 + ac1);
        rb0 = *(const i32x4*)(Wb + (size_t)ar0 * 1024 + k1 + ac0);
        rb1 = *(const i32x4*)(Wb + (size_t)ar1 * 1024 + k1 + ac1);
      }
      i32x4 af[4], bfr[4];
      #pragma unroll
      for (int mi = 0; mi < 4; ++mi)
        af[mi] = *(const i32x4*)(At + (wm * 64 + mi * 16 + lane15) * LDS_STRIDE + lg * 8);
      #pragma unroll
      for (int ni = 0; ni < 4; ++ni)
        bfr[ni] = *(const i32x4*)(Bt + (wn * 64 + ni * 16 + lane15) * LDS_STRIDE + lg * 8);
      #pragma unroll
      for (int mi = 0; mi < 4; ++mi)
        #pragma unroll
        for (int ni = 0; ni < 4; ++ni)
          mfma_bf16(acc[mi][ni], af[mi], bfr[ni]);
    }

    // epilogue: fold tanh(C[m,n]) * wv[n] into per-row partials.
    // C/D layout (m89-verified): col = lane&15, row = (lane>>4)*4 + reg
    float wvn[4];
    #pragma unroll
    for (int ni = 0; ni < 4; ++ni) wvn[ni] = wv[n0 + wn * 64 + ni * 16 + lane15];
    #pragma unroll
    for (int mi = 0; mi < 4; ++mi)
      #pragma unroll
      for (int ni = 0; ni < 4; ++ni)
        #pragma unroll
        for (int r = 0; r < 4; ++r)
          rs[mi][r] += tanh_fast(acc[mi][ni][r]) * wvn[ni];
  }

  // reduce over the 16 column-lanes, combine the two wn halves via LDS
  __syncthreads();
  float* sred = (float*)At;
  #pragma unroll
  for (int mi = 0; mi < 4; ++mi)
    #pragma unroll
    for (int r = 0; r < 4; ++r) {
      float v = rs[mi][r];
      v += __shfl_xor(v, 1);
      v += __shfl_xor(v, 2);
      v += __shfl_xor(v, 4);
      v += __shfl_xor(v, 8);
      if (lane15 == 0) sred[wn * 128 + wm * 64 + mi * 16 + lg * 4 + r] = v;
    }
  __syncthreads();
  if (t < 128) svout[(size_t)split * M + m_base + t] = sred[t] + sred[128 + t];
}

// ------ softmax over a + q-chunk + broadcast q-chunk into output rows ------
// grid: 0..255 audio (b=bx>>4, dch=bx&15) -> out half 1; 256..511 text -> half 0.
__global__ __launch_bounds__(256) void softq_bcast_kernel(
    const float* __restrict__ xA, const float* __restrict__ svA,
    const float* __restrict__ xT, const float* __restrict__ svT,
    float* __restrict__ out) {
  int bx = blockIdx.x;
  int stage = bx >> 8;                  // 0 = audio branch, 1 = text branch
  int b = (bx >> 4) & 15, dch = bx & 15;
  int Acnt = stage ? 1024 : 512;
  int M = stage ? 16384 : 8192;
  const float* x = stage ? xT : xA;
  const float* svp = stage ? svT : svA;
  int rowbase = b * Acnt;

  __shared__ float p[1024];
  __shared__ float red[256];
  __shared__ float chunk[64];
  int t = threadIdx.x;

  float mloc = -1e30f;
  for (int a = t; a < Acnt; a += 256) {
    float v = svp[rowbase + a] + svp[M + rowbase + a] +
              svp[2 * M + rowbase + a] + svp[3 * M + rowbase + a];
    p[a] = v;
    mloc = fmaxf(mloc, v);
  }
  #pragma unroll
  for (int off = 32; off; off >>= 1) mloc = fmaxf(mloc, __shfl_xor(mloc, off));
  if ((t & 63) == 0) red[t >> 6] = mloc;
  __syncthreads();
  float mx = fmaxf(fmaxf(red[0], red[1]), fmaxf(red[2], red[3]));

  float sloc = 0.f;
  for (int a = t; a < Acnt; a += 256) {
    float e = __expf(p[a] - mx);
    p[a] = e;
    sloc += e;
  }
  #pragma unroll
  for (int off = 32; off; off >>= 1) sloc += __shfl_xor(sloc, off);
  __syncthreads();
  if ((t & 63) == 0) red[t >> 6] = sloc;
  __syncthreads();
  float inv = 1.0f / (red[0] + red[1] + red[2] + red[3]);

  int dl = t & 63, ag = t >> 6;
  const float* xb = x + (size_t)rowbase * 1024 + dch * 64 + dl;
  float acc = 0.f;
  #pragma unroll 4
  for (int a = ag; a < Acnt; a += 4) acc += p[a] * xb[(size_t)a * 1024];
  __syncthreads();
  red[t] = acc;
  __syncthreads();
  if (t < 64) {
    float tot = red[t] + red[t + 64] + red[t + 128] + red[t + 192];
    chunk[t] = tot * inv;
  }
  __syncthreads();

  // broadcast this 64-float chunk across all L=1024 rows of the output.
  // out halves: [0] att_text (stage 1), [1] att_audio (stage 0); 16M floats each.
  size_t base4 = ((stage ? (size_t)0 : (size_t)16777216) +
                  (size_t)b * 1048576 + (size_t)dch * 64) >> 2;
  float4* o4 = (float4*)out;
  float4 v = ((float4*)chunk)[t & 15];
  int q = t & 15;
  #pragma unroll 4
  for (int l = t >> 4; l < 1024; l += 16)
    o4[base4 + (size_t)l * 256 + q] = v;
}

extern "C" void kernel_launch(void* const* d_in, const int* in_sizes, int n_in,
                              void* d_out, int out_size, void* d_ws, size_t ws_size,
                              hipStream_t stream) {
  const float* text  = (const float*)d_in[0];   // (16,1024,1024)
  const float* audio = (const float*)d_in[1];   // (16, 512,1024)
  const float* Wa1   = (const float*)d_in[4];   // (1024,1024)
  const float* watt1 = (const float*)d_in[5];   // (2048,)
  const float* Wt2   = (const float*)d_in[7];   // (1024,1024)
  const float* watt2 = (const float*)d_in[10];  // (2048,)

  char* ws = (char*)d_ws;
  u16*   tb  = (u16*)(ws);                      // text bf16   33,554,432 B
  u16*   ab  = (u16*)(ws + 33554432);           // audio bf16  16,777,216 B
  u16*   w2b = (u16*)(ws + 50331648);           // Wt2 bf16     2,097,152 B
  u16*   w1b = (u16*)(ws + 52428800);           // Wa1 bf16     2,097,152 B
  float* sv2 = (float*)(ws + 54525952);         // [4][16384]     262,144 B
  float* sv1 = (float*)(ws + 54788096);         // [4][ 8192]     131,072 B

  cast_all_kernel<<<2048, 256, 0, stream>>>(text, audio, Wt2, Wa1, tb, ab, w2b, w1b);

  score_kernel<<<768, 256, 0, stream>>>(ab, w1b, watt1 + 1024, sv1,
                                        tb, w2b, watt2 + 1024, sv2);

  softq_bcast_kernel<<<512, 256, 0, stream>>>(audio, sv1, text, sv2, (float*)d_out);
}